// Round 1
// baseline (252.361 us; speedup 1.0000x reference)
//
#include <hip/hip_runtime.h>
#include <stdint.h>

typedef short short8 __attribute__((ext_vector_type(8)));
typedef short s16x4 __attribute__((ext_vector_type(4)));
typedef float f32x4 __attribute__((ext_vector_type(4)));

#define NB_H  1024
#define NB_NH 16
#define NB_HD 64
#define NB_B  8
#define NB_S  1024

__device__ __forceinline__ unsigned short f2bf(float f) {
    union { float f; unsigned u; } v; v.f = f;
    unsigned u = v.u;
    return (unsigned short)((u + 0x7fffu + ((u >> 16) & 1u)) >> 16);
}

__device__ __forceinline__ void gload16(const void* g, void* l) {
    __builtin_amdgcn_global_load_lds(
        (const __attribute__((address_space(1))) void*)g,
        (__attribute__((address_space(3))) void*)l,
        16, 0, 0);
}

// ---------------------------------------------------------------- weights fp32->bf16
__global__ __launch_bounds__(256) void wconv_kernel(
    const float* __restrict__ wq, const float* __restrict__ wk, const float* __restrict__ wv,
    short* __restrict__ wbf)
{
    unsigned i = (blockIdx.x * 256u + threadIdx.x) * 4u;  // total 3*1048576 elems
    const float* src = (i < (1u << 20)) ? wq : (i < (2u << 20)) ? wk : wv;
    const float4 v = *(const float4*)(src + (i & 0xFFFFFu));
    s16x4 o;
    o[0] = (short)f2bf(v.x); o[1] = (short)f2bf(v.y);
    o[2] = (short)f2bf(v.z); o[3] = (short)f2bf(v.w);
    *(s16x4*)(wbf + i) = o;
}

// ---------------------------------------------------------------- pos add + LayerNorm -> bf16
__global__ __launch_bounds__(256) void posln_kernel(
    const float* __restrict__ hs, const float* __restrict__ pos,
    const float* __restrict__ lnw, const float* __restrict__ lnb,
    short* __restrict__ xbf)
{
    const int row = blockIdx.x;            // 0..8191 = b*1024 + s
    const int s   = row & 1023;
    const int t   = threadIdx.x;
    const int wave = t >> 6, lane = t & 63;

    float4 x4 = *(const float4*)(hs  + (size_t)row * 1024 + t * 4);
    float4 p4 = *(const float4*)(pos + (size_t)s   * 1024 + t * 4);
    float v0 = x4.x + p4.x, v1 = x4.y + p4.y, v2 = x4.z + p4.z, v3 = x4.w + p4.w;

    float sum = v0 + v1 + v2 + v3;
    #pragma unroll
    for (int o = 1; o < 64; o <<= 1) sum += __shfl_xor(sum, o, 64);
    __shared__ float red[4];
    __shared__ float red2[4];
    if (lane == 0) red[wave] = sum;
    __syncthreads();
    float mu = (red[0] + red[1] + red[2] + red[3]) * (1.0f / 1024.0f);

    float d0 = v0 - mu, d1 = v1 - mu, d2 = v2 - mu, d3 = v3 - mu;
    float sq = d0 * d0 + d1 * d1 + d2 * d2 + d3 * d3;
    #pragma unroll
    for (int o = 1; o < 64; o <<= 1) sq += __shfl_xor(sq, o, 64);
    if (lane == 0) red2[wave] = sq;
    __syncthreads();
    float var = (red2[0] + red2[1] + red2[2] + red2[3]) * (1.0f / 1024.0f);
    float rs = rsqrtf(var + 1e-12f);

    const float4 w4 = *(const float4*)(lnw + t * 4);
    const float4 b4 = *(const float4*)(lnb + t * 4);
    s16x4 o;
    o[0] = (short)f2bf(d0 * rs * w4.x + b4.x);
    o[1] = (short)f2bf(d1 * rs * w4.y + b4.y);
    o[2] = (short)f2bf(d2 * rs * w4.z + b4.z);
    o[3] = (short)f2bf(d3 * rs * w4.w + b4.w);
    *(s16x4*)(xbf + (size_t)row * 1024 + t * 4) = o;
}

// ---------------------------------------------------------------- QKV GEMM (m97 structure)
// C[m][n] = sum_k x[m][k] * W[n][k] + bias[n];  M=8192, N=3072, K=1024
// epilogue scatters to q[bh][s][d], k[bh][s][d], vT[bh][d][s]  (bf16)
__global__ __launch_bounds__(256, 2) void qkv_gemm(
    const short* __restrict__ xbf,   // [8192][1024]
    const short* __restrict__ wbf,   // [3072][1024]
    const float* __restrict__ bq, const float* __restrict__ bk, const float* __restrict__ bv,
    short* __restrict__ q_bf, short* __restrict__ k_bf, short* __restrict__ vt_bf)
{
    __shared__ short lds_a[128 * 32];
    __shared__ short lds_b[128 * 32];
    const int tid = threadIdx.x;
    const int wave = tid >> 6, lane = tid & 63;
    const int l15 = lane & 15, l4 = lane >> 4;
    const int m0 = blockIdx.x * 128;
    const int n0 = blockIdx.y * 128;
    const int wr = wave >> 1, wc = wave & 1;

    f32x4 acc[4][4] = {};

    for (int kt = 0; kt < 32; ++kt) {
        const int k0 = kt * 32;
        __syncthreads();
        #pragma unroll
        for (int c = 0; c < 2; ++c) {
            const int ch = (c * 4 + wave) * 64 + lane;      // 16B chunk index 0..511
            const int row = ch >> 2, kc = ch & 3;
            gload16(xbf + (size_t)(m0 + row) * 1024 + k0 + kc * 8,
                    lds_a + (size_t)(c * 4 + wave) * 512);
            gload16(wbf + (size_t)(n0 + row) * 1024 + k0 + kc * 8,
                    lds_b + (size_t)(c * 4 + wave) * 512);
        }
        __syncthreads();
        short8 af[4], bfr[4];
        #pragma unroll
        for (int mi = 0; mi < 4; ++mi)
            af[mi] = *(const short8*)(lds_a + (wr * 64 + mi * 16 + l15) * 32 + l4 * 8);
        #pragma unroll
        for (int nj = 0; nj < 4; ++nj)
            bfr[nj] = *(const short8*)(lds_b + (wc * 64 + nj * 16 + l15) * 32 + l4 * 8);
        #pragma unroll
        for (int mi = 0; mi < 4; ++mi)
            #pragma unroll
            for (int nj = 0; nj < 4; ++nj)
                acc[mi][nj] = __builtin_amdgcn_mfma_f32_16x16x32_bf16(af[mi], bfr[nj], acc[mi][nj], 0, 0, 0);
    }

    #pragma unroll
    for (int mi = 0; mi < 4; ++mi)
        #pragma unroll
        for (int nj = 0; nj < 4; ++nj) {
            const int n = n0 + wc * 64 + nj * 16 + l15;
            const int which = n >> 10;
            const int hh = (n >> 6) & 15, dd = n & 63, nn = n & 1023;
            const float bias = (which == 0) ? bq[nn] : (which == 1) ? bk[nn] : bv[nn];
            #pragma unroll
            for (int r = 0; r < 4; ++r) {
                const int m = m0 + wr * 64 + mi * 16 + l4 * 4 + r;
                const int bi = m >> 10, s = m & 1023;
                const short hv = (short)f2bf(acc[mi][nj][r] + bias);
                if (which == 0)      q_bf[(size_t)((bi * 16 + hh) * 1024 + s) * 64 + dd] = hv;
                else if (which == 1) k_bf[(size_t)((bi * 16 + hh) * 1024 + s) * 64 + dd] = hv;
                else                 vt_bf[(size_t)((bi * 16 + hh) * 64 + dd) * 1024 + s] = hv;
            }
        }
}

// ---------------------------------------------------------------- flash attention
// grid (8, 128): x = q-tile (128 rows), y = b*16+h. 4 waves x 32 q-rows.
__global__ __launch_bounds__(256, 2) void attn_kernel(
    const short* __restrict__ q_bf, const short* __restrict__ k_bf,
    const short* __restrict__ vt_bf, float* __restrict__ out)
{
    __shared__ short p_lds[4][32 * 64];   // per-wave P tile, 16 KB
    const int qt = blockIdx.x, bh = blockIdx.y;
    const int bi = bh >> 4, hh = bh & 15;
    const int tid = threadIdx.x, wave = tid >> 6, lane = tid & 63;
    const int l15 = lane & 15, l4 = lane >> 4;
    const int qrow0 = qt * 128 + wave * 32;

    const short* qb = q_bf  + (size_t)bh * NB_S * NB_HD;
    const short* kb = k_bf  + (size_t)bh * NB_S * NB_HD;
    const short* vb = vt_bf + (size_t)bh * NB_HD * NB_S;

    short8 qa[2][2];
    #pragma unroll
    for (int mi = 0; mi < 2; ++mi)
        #pragma unroll
        for (int ks = 0; ks < 2; ++ks)
            qa[mi][ks] = *(const short8*)(qb + (size_t)(qrow0 + mi * 16 + l15) * 64 + ks * 32 + l4 * 8);

    f32x4 oacc[2][4] = {};
    float mrun[2][4], lsum[2][4];
    #pragma unroll
    for (int mi = 0; mi < 2; ++mi)
        #pragma unroll
        for (int r = 0; r < 4; ++r) { mrun[mi][r] = -1e30f; lsum[mi][r] = 0.0f; }

    for (int kbk = 0; kbk < 16; ++kbk) {
        const int key0 = kbk * 64;
        short8 kf[4][2];
        #pragma unroll
        for (int kt = 0; kt < 4; ++kt)
            #pragma unroll
            for (int ks = 0; ks < 2; ++ks)
                kf[kt][ks] = *(const short8*)(kb + (size_t)(key0 + kt * 16 + l15) * 64 + ks * 32 + l4 * 8);

        f32x4 sacc[2][4] = {};
        #pragma unroll
        for (int mi = 0; mi < 2; ++mi)
            #pragma unroll
            for (int kt = 0; kt < 4; ++kt)
                #pragma unroll
                for (int ks = 0; ks < 2; ++ks)
                    sacc[mi][kt] = __builtin_amdgcn_mfma_f32_16x16x32_bf16(qa[mi][ks], kf[kt][ks], sacc[mi][kt], 0, 0, 0);

        float fac[2][4];
        #pragma unroll
        for (int mi = 0; mi < 2; ++mi)
            #pragma unroll
            for (int r = 0; r < 4; ++r) {
                #pragma unroll
                for (int kt = 0; kt < 4; ++kt) sacc[mi][kt][r] *= 0.125f;
                float tm = fmaxf(fmaxf(sacc[mi][0][r], sacc[mi][1][r]), fmaxf(sacc[mi][2][r], sacc[mi][3][r]));
                #pragma unroll
                for (int o = 1; o < 16; o <<= 1) tm = fmaxf(tm, __shfl_xor(tm, o, 64));
                const float mnew = fmaxf(mrun[mi][r], tm);
                fac[mi][r] = __expf(mrun[mi][r] - mnew);
                mrun[mi][r] = mnew;
                float rsum = 0.0f;
                #pragma unroll
                for (int kt = 0; kt < 4; ++kt) {
                    const float p = __expf(sacc[mi][kt][r] - mnew);
                    sacc[mi][kt][r] = p;
                    rsum += p;
                }
                #pragma unroll
                for (int o = 1; o < 16; o <<= 1) rsum += __shfl_xor(rsum, o, 64);
                lsum[mi][r] = lsum[mi][r] * fac[mi][r] + rsum;
            }

        #pragma unroll
        for (int mi = 0; mi < 2; ++mi)
            #pragma unroll
            for (int nj = 0; nj < 4; ++nj)
                #pragma unroll
                for (int r = 0; r < 4; ++r) oacc[mi][nj][r] *= fac[mi][r];

        #pragma unroll
        for (int mi = 0; mi < 2; ++mi)
            #pragma unroll
            for (int kt = 0; kt < 4; ++kt)
                #pragma unroll
                for (int r = 0; r < 4; ++r)
                    p_lds[wave][(mi * 16 + l4 * 4 + r) * 64 + kt * 16 + l15] = (short)f2bf(sacc[mi][kt][r]);
        __syncthreads();

        short8 pa[2][2], vf[4][2];
        #pragma unroll
        for (int mi = 0; mi < 2; ++mi)
            #pragma unroll
            for (int kc = 0; kc < 2; ++kc)
                pa[mi][kc] = *(const short8*)(&p_lds[wave][(mi * 16 + l15) * 64 + kc * 32 + l4 * 8]);
        #pragma unroll
        for (int nj = 0; nj < 4; ++nj)
            #pragma unroll
            for (int kc = 0; kc < 2; ++kc)
                vf[nj][kc] = *(const short8*)(vb + (size_t)(nj * 16 + l15) * 1024 + key0 + kc * 32 + l4 * 8);
        #pragma unroll
        for (int mi = 0; mi < 2; ++mi)
            #pragma unroll
            for (int nj = 0; nj < 4; ++nj)
                #pragma unroll
                for (int kc = 0; kc < 2; ++kc)
                    oacc[mi][nj] = __builtin_amdgcn_mfma_f32_16x16x32_bf16(pa[mi][kc], vf[nj][kc], oacc[mi][nj], 0, 0, 0);
        __syncthreads();
    }

    #pragma unroll
    for (int mi = 0; mi < 2; ++mi)
        #pragma unroll
        for (int nj = 0; nj < 4; ++nj)
            #pragma unroll
            for (int r = 0; r < 4; ++r) {
                const int srow = qrow0 + mi * 16 + l4 * 4 + r;
                out[((size_t)bi * 1024 + srow) * 1024 + hh * 64 + nj * 16 + l15] =
                    oacc[mi][nj][r] / lsum[mi][r];
            }
}

extern "C" void kernel_launch(void* const* d_in, const int* in_sizes, int n_in,
                              void* d_out, int out_size, void* d_ws, size_t ws_size,
                              hipStream_t stream) {
    const float* hs  = (const float*)d_in[0];
    const float* pos = (const float*)d_in[1];
    const float* lnw = (const float*)d_in[2];
    const float* lnb = (const float*)d_in[3];
    const float* wq  = (const float*)d_in[4];
    const float* bq  = (const float*)d_in[5];
    const float* wk  = (const float*)d_in[6];
    const float* bk  = (const float*)d_in[7];
    const float* wv  = (const float*)d_in[8];
    const float* bv  = (const float*)d_in[9];
    float* out = (float*)d_out;

    char* ws = (char*)d_ws;
    short* wbf  = (short*)(ws);                                  // 6,291,456 B
    short* xbf  = (short*)(ws + 6291456);                        // 16,777,216 B
    short* qbf  = (short*)(ws + 6291456 + 16777216);             // 16,777,216 B
    short* kbf  = (short*)(ws + 6291456 + 2 * 16777216);         // 16,777,216 B
    short* vtbf = (short*)(ws + 6291456 + 3 * 16777216);         // 16,777,216 B

    wconv_kernel<<<dim3(3072), dim3(256), 0, stream>>>(wq, wk, wv, wbf);
    posln_kernel<<<dim3(8192), dim3(256), 0, stream>>>(hs, pos, lnw, lnb, xbf);
    qkv_gemm<<<dim3(64, 24), dim3(256), 0, stream>>>(xbf, wbf, bq, bk, bv, qbf, kbf, vtbf);
    attn_kernel<<<dim3(8, 128), dim3(256), 0, stream>>>(qbf, kbf, vtbf, out);
}